// Round 5
// baseline (188.864 us; speedup 1.0000x reference)
//
#include <hip/hip_runtime.h>
#include <hip/hip_bf16.h>

namespace {

constexpr int Bn = 4, Nn = 4096, An = 64;

typedef __attribute__((ext_vector_type(8))) short bf16x8;
typedef __attribute__((ext_vector_type(4))) float f32x4;

constexpr float QSCALE = 0.125f * 1.4426950408889634f;  // 1/sqrt(A) * log2(e)

__device__ __forceinline__ short f2bf(float f) {
    __hip_bfloat16 h = __float2bfloat16(f);
    return *reinterpret_cast<short*>(&h);
}
__device__ __forceinline__ float bf2f(short s) {
    unsigned u = ((unsigned)(unsigned short)s) << 16;
    return *reinterpret_cast<float*>(&u);
}
__device__ __forceinline__ unsigned pack2bf(float a, float b) {
    return (unsigned)(unsigned short)f2bf(a) | ((unsigned)(unsigned short)f2bf(b) << 16);
}

// ---------------------------------------------------------------------------
// Kernel 0: pack W -> Wt[192][512] bf16. cols 0-63 Wq*QSCALE, 64-127 Wk,
// 128-191 Wv. Bias bc[192]. Lives in d_out scratch (consumed before attn).
// ---------------------------------------------------------------------------
__global__ __launch_bounds__(256) void wpack(
    const float* __restrict__ Wq, const float* __restrict__ bq,
    const float* __restrict__ Wk, const float* __restrict__ bk,
    const float* __restrict__ Wv, const float* __restrict__ bv,
    short* __restrict__ Wt, float* __restrict__ bc)
{
    const int tid = blockIdx.x * 256 + threadIdx.x;   // 12288
    const int c = tid >> 6, k0 = (tid & 63) << 3;
    const int m = c >> 6, a = c & 63;
    const float* W = (m == 0) ? Wq : (m == 1) ? Wk : Wv;
    const float s = (m == 0) ? QSCALE : 1.0f;
    bf16x8 o;
    #pragma unroll
    for (int j = 0; j < 8; ++j) o[j] = f2bf(W[(size_t)(k0 + j) * 64 + a] * s);
    *reinterpret_cast<bf16x8*>(Wt + (size_t)c * 512 + k0) = o;
    if (tid < 192) bc[tid] = (m == 0) ? bq[a] * QSCALE : (m == 1) ? bk[a] : bv[a];
}

// ---------------------------------------------------------------------------
// Kernel 1: QKV projection GEMM, barrier-free / TLP-hiding version.
// One wave = 16 rows x 64 cols; 3072 waves = 768 blocks (3 blocks/CU).
// Wt (196 KB, L2-resident) fragments read directly from L2 each K-step.
// x read once (hi/lo bf16 split for fp32-quality accumulate).
// V output transposed per-wave through a private LDS tile (no barriers).
// ---------------------------------------------------------------------------
__global__ __launch_bounds__(256) void qkv_mm(
    const float* __restrict__ x, const short* __restrict__ Wt,
    const float* __restrict__ bc,
    __hip_bfloat16* __restrict__ Qb, __hip_bfloat16* __restrict__ Kb,
    __hip_bfloat16* __restrict__ Vt)
{
    __shared__ __align__(16) short vt[4][16 * 64];   // per-wave V transpose tile

    const int tid  = threadIdx.x;
    const int w    = tid >> 6, lane = tid & 63;
    const int lo   = lane & 15, g = lane >> 4;
    const int gw   = blockIdx.x * 4 + w;            // 0..3071
    const int rowgrp = gw / 3;                      // 0..1023
    const int colgrp = gw - rowgrp * 3;             // 0..2 (Q / K / V)
    const int r0   = rowgrp * 16;
    const int c0   = colgrp * 64;

    const float* xr = x  + (size_t)(r0 + lo) * 512 + 8 * g;
    const short* wp = Wt + (size_t)(c0 + lo) * 512 + 8 * g;

    f32x4 acc[4];
    #pragma unroll
    for (int i = 0; i < 4; ++i) acc[i] = f32x4{0.f, 0.f, 0.f, 0.f};

    #pragma unroll 4
    for (int kt = 0; kt < 512; kt += 32) {
        float4 a0 = *reinterpret_cast<const float4*>(xr + kt);
        float4 a1 = *reinterpret_cast<const float4*>(xr + kt + 4);
        float xf[8] = {a0.x, a0.y, a0.z, a0.w, a1.x, a1.y, a1.z, a1.w};
        bf16x8 ah, al;
        #pragma unroll
        for (int j = 0; j < 8; ++j) {
            short h = f2bf(xf[j]);
            ah[j] = h;
            al[j] = f2bf(xf[j] - bf2f(h));
        }
        #pragma unroll
        for (int ct = 0; ct < 4; ++ct) {
            bf16x8 wf = *reinterpret_cast<const bf16x8*>(wp + (size_t)ct * 16 * 512 + kt);
            acc[ct] = __builtin_amdgcn_mfma_f32_16x16x32_bf16(ah, wf, acc[ct], 0, 0, 0);
            acc[ct] = __builtin_amdgcn_mfma_f32_16x16x32_bf16(al, wf, acc[ct], 0, 0, 0);
        }
    }

    // C-frag: col = lane&15, row = 4*(lane>>4)+reg  [guide m89]
    const int bb = r0 >> 12, n0 = r0 & 4095;
    if (colgrp < 2) {
        __hip_bfloat16* dst = (colgrp == 0) ? Qb : Kb;
        #pragma unroll
        for (int ct = 0; ct < 4; ++ct) {
            const float bias = bc[c0 + ct * 16 + lo];
            #pragma unroll
            for (int r = 0; r < 4; ++r) {
                short hv = f2bf(acc[ct][r] + bias);
                dst[(size_t)(r0 + 4 * g + r) * 64 + ct * 16 + lo] =
                    *reinterpret_cast<__hip_bfloat16*>(&hv);
            }
        }
    } else {
        #pragma unroll
        for (int ct = 0; ct < 4; ++ct) {
            const float bias = bc[128 + ct * 16 + lo];
            #pragma unroll
            for (int r = 0; r < 4; ++r)
                vt[w][(4 * g + r) * 64 + ct * 16 + lo] = f2bf(acc[ct][r] + bias);
        }
        asm volatile("s_waitcnt lgkmcnt(0)" ::: "memory");
        __builtin_amdgcn_sched_barrier(0);
        // lane = output channel a; gather its 16 n-values (2-way bank alias: free)
        unsigned u[8];
        #pragma unroll
        for (int n = 0; n < 8; ++n) {
            unsigned v0 = (unsigned short)vt[w][(2 * n) * 64 + lane];
            unsigned v1 = (unsigned short)vt[w][(2 * n + 1) * 64 + lane];
            u[n] = v0 | (v1 << 16);
        }
        uint4* dstv = reinterpret_cast<uint4*>(&Vt[((size_t)(bb * 64 + lane)) * 4096 + n0]);
        dstv[0] = uint4{u[0], u[1], u[2], u[3]};
        dstv[1] = uint4{u[4], u[5], u[6], u[7]};
    }
}

// ---------------------------------------------------------------------------
// Kernel 2: flash attention (no online max; scores bounded -> exp2 direct).
// WAVES waves/block, each wave 32 q-rows (2 q-tiles). K/V double-buffered in
// swizzled LDS shared by all waves. Swapped QK^T: cc = mfma(K,Q) so the P^T
// transpose to PV-A/B-frags is 4 ds_write_b64 + 2 ds_read_b128 per q-tile.
// KS=8 -> 512 blocks, 2 blocks/CU, 4 waves/SIMD (latency hiding).
// ---------------------------------------------------------------------------
template<int WAVES, int KS, bool DIRECT>
__global__ __launch_bounds__(WAVES * 64, 4) void attn(
    const __hip_bfloat16* __restrict__ Qb,
    const __hip_bfloat16* __restrict__ Kb,
    const __hip_bfloat16* __restrict__ Vt,
    float* __restrict__ Pacc, float* __restrict__ Lbuf, float* __restrict__ outD)
{
    constexpr int T    = WAVES * 64;
    constexpr int QPB  = WAVES * 32;
    constexpr int SBPB = Nn / QPB;
    constexpr int QSBC = (Bn * Nn) / QPB;
    constexpr int NC   = 512 / T;      // staging chunks per thread

    __shared__ __align__(16) short Klds[2][64 * 64];
    __shared__ __align__(16) short Vlds[2][64 * 64];
    __shared__ __align__(16) short Plds[WAVES][16 * 64];

    const int tid  = threadIdx.x;
    const int w    = tid >> 6, lane = tid & 63;
    const int lo   = lane & 15, g = lane >> 4;
    const int qsb  = blockIdx.x % QSBC;
    const int ks   = blockIdx.x / QSBC;
    const int b    = qsb / SBPB;
    const int nqb  = (qsb % SBPB) * QPB;
    const int k0b  = ks * (Nn / KS);
    const int nsteps = (Nn / KS) / 64;

    bf16x8 qf[2][2];
    #pragma unroll
    for (int qt = 0; qt < 2; ++qt)
        #pragma unroll
        for (int dh = 0; dh < 2; ++dh)
            qf[qt][dh] = *reinterpret_cast<const bf16x8*>(
                &Qb[(size_t)(b * Nn + nqb + w * 32 + qt * 16 + lo) * 64 + dh * 32 + 8 * g]);

    f32x4 acc[2][4];
    #pragma unroll
    for (int q = 0; q < 2; ++q)
        #pragma unroll
        for (int a = 0; a < 4; ++a) acc[q][a] = f32x4{0.f, 0.f, 0.f, 0.f};
    float lsum[2] = {0.f, 0.f};

    uint4 kr[NC], vr[NC];
    auto stg_issue = [&](int s) {
        int k0 = k0b + s * 64;
        #pragma unroll
        for (int i = 0; i < NC; ++i) {
            int c = i * T + tid, key = c >> 3, sl = c & 7;
            kr[i] = *reinterpret_cast<const uint4*>(&Kb[(size_t)(b * Nn + k0 + key) * 64 + sl * 8]);
            vr[i] = *reinterpret_cast<const uint4*>(&Vt[(size_t)(b * 64 + key) * Nn + k0 + sl * 8]);
        }
    };
    auto stg_write = [&](int buf) {
        #pragma unroll
        for (int i = 0; i < NC; ++i) {
            int c = i * T + tid, key = c >> 3, ss = (c & 7) ^ (key & 7);
            *reinterpret_cast<uint4*>(&Klds[buf][key * 64 + ss * 8]) = kr[i];
            *reinterpret_cast<uint4*>(&Vlds[buf][key * 64 + ss * 8]) = vr[i];
        }
    };

    auto step = [&](int buf) {
        bf16x8 ka[4][2], va[4][2];
        #pragma unroll
        for (int t = 0; t < 4; ++t)
            #pragma unroll
            for (int dh = 0; dh < 2; ++dh) {
                int row = lo + 16 * t, ss = (g + 4 * dh) ^ (row & 7);
                ka[t][dh] = *reinterpret_cast<const bf16x8*>(&Klds[buf][row * 64 + ss * 8]);
            }
        #pragma unroll
        for (int at = 0; at < 4; ++at)
            #pragma unroll
            for (int c = 0; c < 2; ++c) {
                int row = at * 16 + lo, ss = (4 * c + g) ^ (row & 7);
                va[at][c] = *reinterpret_cast<const bf16x8*>(&Vlds[buf][row * 64 + ss * 8]);
            }
        char* pbase = reinterpret_cast<char*>(&Plds[w][0]) + lo * 128;
        #pragma unroll
        for (int qt = 0; qt < 2; ++qt) {
            f32x4 cc[4];
            __builtin_amdgcn_s_setprio(1);
            #pragma unroll
            for (int t = 0; t < 4; ++t) {
                cc[t] = f32x4{0.f, 0.f, 0.f, 0.f};
                cc[t] = __builtin_amdgcn_mfma_f32_16x16x32_bf16(ka[t][0], qf[qt][0], cc[t], 0, 0, 0);
                cc[t] = __builtin_amdgcn_mfma_f32_16x16x32_bf16(ka[t][1], qf[qt][1], cc[t], 0, 0, 0);
            }
            __builtin_amdgcn_s_setprio(0);
            #pragma unroll
            for (int t = 0; t < 4; ++t) {
                float p0 = exp2f(cc[t][0]), p1 = exp2f(cc[t][1]);
                float p2 = exp2f(cc[t][2]), p3 = exp2f(cc[t][3]);
                lsum[qt] += (p0 + p1) + (p2 + p3);
                uint2 pw = {pack2bf(p0, p1), pack2bf(p2, p3)};
                int byte = (32 * t + 8 * g) ^ ((lo & 7) << 4);
                *reinterpret_cast<uint2*>(pbase + byte) = pw;
            }
            asm volatile("s_waitcnt lgkmcnt(0)" ::: "memory");
            bf16x8 pb[2];
            #pragma unroll
            for (int c = 0; c < 2; ++c) {
                int byte = (64 * c + 16 * g) ^ ((lo & 7) << 4);
                pb[c] = *reinterpret_cast<const bf16x8*>(pbase + byte);
            }
            __builtin_amdgcn_s_setprio(1);
            #pragma unroll
            for (int at = 0; at < 4; ++at) {
                acc[qt][at] = __builtin_amdgcn_mfma_f32_16x16x32_bf16(va[at][0], pb[0], acc[qt][at], 0, 0, 0);
                acc[qt][at] = __builtin_amdgcn_mfma_f32_16x16x32_bf16(va[at][1], pb[1], acc[qt][at], 0, 0, 0);
            }
            __builtin_amdgcn_s_setprio(0);
        }
    };

    stg_issue(0);
    stg_write(0);
    __syncthreads();
    for (int s = 0; s < nsteps; ++s) {
        if (s + 1 < nsteps) stg_issue(s + 1);
        step(s & 1);
        if (s + 1 < nsteps) {
            __syncthreads();
            stg_write((s + 1) & 1);
            __syncthreads();
        }
    }

    #pragma unroll
    for (int qt = 0; qt < 2; ++qt) {
        float l = lsum[qt];
        l += __shfl_xor(l, 16);
        l += __shfl_xor(l, 32);
        const int n = nqb + w * 32 + qt * 16 + lo;
        if (!DIRECT) {
            if (g == 0) Lbuf[(size_t)(ks * Bn + b) * Nn + n] = l;
            #pragma unroll
            for (int at = 0; at < 4; ++at)
                #pragma unroll
                for (int r = 0; r < 4; ++r) {
                    int a = at * 16 + 4 * g + r;
                    Pacc[((size_t)(ks * Bn + b) * An + a) * Nn + n] = acc[qt][at][r];
                }
        } else {
            float inv = 1.0f / l;
            #pragma unroll
            for (int at = 0; at < 4; ++at)
                #pragma unroll
                for (int r = 0; r < 4; ++r)
                    outD[((size_t)(b * Nn) + n) * 64 + at * 16 + 4 * g + r] = acc[qt][at][r] * inv;
        }
    }
}

// ---------------------------------------------------------------------------
// Kernel 3: combine key-split partials, normalize, transpose [a][n] -> [n][a].
// Grid 256 = 4 b x 64 n-tiles. Coalesced reads (along n) and writes (along a).
// ---------------------------------------------------------------------------
__global__ __launch_bounds__(256) void reduce_out(
    const float* __restrict__ Pacc, const float* __restrict__ Lbuf,
    float* __restrict__ out, int KS)
{
    __shared__ float sa[64][65];
    __shared__ float sl[64];
    const int b = blockIdx.x >> 6, n0 = (blockIdx.x & 63) * 64;
    const int t = threadIdx.x;

    float r[16];
    #pragma unroll
    for (int i = 0; i < 16; ++i) r[i] = 0.f;
    for (int s = 0; s < KS; ++s) {
        const float* P = Pacc + (size_t)(s * Bn + b) * An * Nn;
        #pragma unroll
        for (int i = 0; i < 16; ++i) {
            int idx = i * 256 + t;
            r[i] += P[(size_t)(idx >> 6) * Nn + n0 + (idx & 63)];
        }
    }
    #pragma unroll
    for (int i = 0; i < 16; ++i) { int idx = i * 256 + t; sa[idx >> 6][idx & 63] = r[i]; }
    if (t < 64) {
        float lv = 0.f;
        for (int s = 0; s < KS; ++s) lv += Lbuf[(size_t)(s * Bn + b) * Nn + n0 + t];
        sl[t] = 1.0f / lv;
    }
    __syncthreads();
    #pragma unroll
    for (int i = 0; i < 4; ++i) {
        int chunk = i * 256 + t, row = chunk >> 4, c4 = chunk & 15;
        float inv = sl[row];
        float4 v;
        v.x = sa[c4 * 4 + 0][row] * inv;
        v.y = sa[c4 * 4 + 1][row] * inv;
        v.z = sa[c4 * 4 + 2][row] * inv;
        v.w = sa[c4 * 4 + 3][row] * inv;
        *reinterpret_cast<float4*>(&out[((size_t)b * Nn + n0 + row) * 64 + c4 * 4]) = v;
    }
}

} // anonymous namespace

extern "C" void kernel_launch(void* const* d_in, const int* in_sizes, int n_in,
                              void* d_out, int out_size, void* d_ws, size_t ws_size,
                              hipStream_t stream) {
    const float* x  = (const float*)d_in[0];
    const float* Wq = (const float*)d_in[1];
    const float* bq = (const float*)d_in[2];
    const float* Wk = (const float*)d_in[3];
    const float* bk = (const float*)d_in[4];
    const float* Wv = (const float*)d_in[5];
    const float* bv = (const float*)d_in[6];
    float* out = (float*)d_out;

    char* ws = (char*)d_ws;
    const size_t mat_bytes = (size_t)Bn * Nn * An * sizeof(__hip_bfloat16);  // 2 MiB
    __hip_bfloat16* Qb = (__hip_bfloat16*)(ws);
    __hip_bfloat16* Kb = (__hip_bfloat16*)(ws + mat_bytes);
    __hip_bfloat16* Vt = (__hip_bfloat16*)(ws + 2 * mat_bytes);
    float* Pacc = (float*)(ws + 3 * mat_bytes);
    const size_t pacc_bytes = (size_t)Bn * An * Nn * sizeof(float);          // 4 MiB per split
    const size_t lbuf_per   = (size_t)Bn * Nn * sizeof(float);               // 64 KiB per split

    // weight-pack scratch in d_out (consumed by qkv_mm, later overwritten)
    short* Wt = (short*)d_out;
    float* bc = (float*)((char*)d_out + 192 * 512 * 2);

    wpack<<<dim3(48), dim3(256), 0, stream>>>(Wq, bq, Wk, bk, Wv, bv, Wt, bc);
    qkv_mm<<<dim3(768), dim3(256), 0, stream>>>(x, Wt, bc, Qb, Kb, Vt);

    const size_t base = 3 * mat_bytes;
    if (ws_size >= base + 8 * pacc_bytes + 8 * lbuf_per) {
        float* Lbuf = (float*)(ws + base + 8 * pacc_bytes);
        attn<8, 8, false><<<dim3((Bn * Nn / 256) * 8), dim3(512), 0, stream>>>(Qb, Kb, Vt, Pacc, Lbuf, out);
        reduce_out<<<dim3(256), dim3(256), 0, stream>>>(Pacc, Lbuf, out, 8);
    } else if (ws_size >= base + 4 * pacc_bytes + 4 * lbuf_per) {
        float* Lbuf = (float*)(ws + base + 4 * pacc_bytes);
        attn<8, 4, false><<<dim3((Bn * Nn / 256) * 4), dim3(512), 0, stream>>>(Qb, Kb, Vt, Pacc, Lbuf, out);
        reduce_out<<<dim3(256), dim3(256), 0, stream>>>(Pacc, Lbuf, out, 4);
    } else {
        attn<4, 1, true><<<dim3(Bn * Nn / 128), dim3(256), 0, stream>>>(Qb, Kb, Vt, nullptr, nullptr, out);
    }
}

// Round 6
// 109.095 us; speedup vs baseline: 1.7312x; 1.7312x over previous
//
#include <hip/hip_runtime.h>
#include <hip/hip_bf16.h>

namespace {

constexpr int Bn = 4, Nn = 4096, An = 64;

typedef __attribute__((ext_vector_type(8))) short bf16x8;
typedef __attribute__((ext_vector_type(4))) float f32x4;

constexpr float QSCALE = 0.125f * 1.4426950408889634f;  // 1/sqrt(A) * log2(e)

__device__ __forceinline__ short f2bf(float f) {
    __hip_bfloat16 h = __float2bfloat16(f);
    return *reinterpret_cast<short*>(&h);
}
__device__ __forceinline__ float bf2f(short s) {
    unsigned u = ((unsigned)(unsigned short)s) << 16;
    return *reinterpret_cast<float*>(&u);
}
__device__ __forceinline__ unsigned pack2bf(float a, float b) {
    return (unsigned)(unsigned short)f2bf(a) | ((unsigned)(unsigned short)f2bf(b) << 16);
}

// ---------------------------------------------------------------------------
// Kernel 0: pack W -> Wt[192][512] bf16. cols 0-63 Wq*QSCALE, 64-127 Wk,
// 128-191 Wv. Bias bc[192]. Lives in d_out scratch (consumed before attn).
// ---------------------------------------------------------------------------
__global__ __launch_bounds__(256) void wpack(
    const float* __restrict__ Wq, const float* __restrict__ bq,
    const float* __restrict__ Wk, const float* __restrict__ bk,
    const float* __restrict__ Wv, const float* __restrict__ bv,
    short* __restrict__ Wt, float* __restrict__ bc)
{
    const int tid = blockIdx.x * 256 + threadIdx.x;   // 12288
    const int c = tid >> 6, k0 = (tid & 63) << 3;
    const int m = c >> 6, a = c & 63;
    const float* W = (m == 0) ? Wq : (m == 1) ? Wk : Wv;
    const float s = (m == 0) ? QSCALE : 1.0f;
    bf16x8 o;
    #pragma unroll
    for (int j = 0; j < 8; ++j) o[j] = f2bf(W[(size_t)(k0 + j) * 64 + a] * s);
    *reinterpret_cast<bf16x8*>(Wt + (size_t)c * 512 + k0) = o;
    if (tid < 192) bc[tid] = (m == 0) ? bq[a] * QSCALE : (m == 1) ? bk[a] : bv[a];
}

// ---------------------------------------------------------------------------
// Kernel 1: QKV projection GEMM, barrier-free / TLP-hiding version.
// One wave = 16 rows x 64 cols; 3072 waves = 768 blocks (3 blocks/CU).
// Wt (196 KB, L2-resident) fragments read directly from L2 each K-step.
// x read once (hi/lo bf16 split for fp32-quality accumulate).
// V output transposed per-wave through a private LDS tile (no barriers).
// ---------------------------------------------------------------------------
__global__ __launch_bounds__(256) void qkv_mm(
    const float* __restrict__ x, const short* __restrict__ Wt,
    const float* __restrict__ bc,
    __hip_bfloat16* __restrict__ Qb, __hip_bfloat16* __restrict__ Kb,
    __hip_bfloat16* __restrict__ Vt)
{
    __shared__ __align__(16) short vt[4][16 * 64];   // per-wave V transpose tile

    const int tid  = threadIdx.x;
    const int w    = tid >> 6, lane = tid & 63;
    const int lo   = lane & 15, g = lane >> 4;
    const int gw   = blockIdx.x * 4 + w;            // 0..3071
    const int rowgrp = gw / 3;                      // 0..1023
    const int colgrp = gw - rowgrp * 3;             // 0..2 (Q / K / V)
    const int r0   = rowgrp * 16;
    const int c0   = colgrp * 64;

    const float* xr = x  + (size_t)(r0 + lo) * 512 + 8 * g;
    const short* wp = Wt + (size_t)(c0 + lo) * 512 + 8 * g;

    f32x4 acc[4];
    #pragma unroll
    for (int i = 0; i < 4; ++i) acc[i] = f32x4{0.f, 0.f, 0.f, 0.f};

    #pragma unroll 4
    for (int kt = 0; kt < 512; kt += 32) {
        float4 a0 = *reinterpret_cast<const float4*>(xr + kt);
        float4 a1 = *reinterpret_cast<const float4*>(xr + kt + 4);
        float xf[8] = {a0.x, a0.y, a0.z, a0.w, a1.x, a1.y, a1.z, a1.w};
        bf16x8 ah, al;
        #pragma unroll
        for (int j = 0; j < 8; ++j) {
            short h = f2bf(xf[j]);
            ah[j] = h;
            al[j] = f2bf(xf[j] - bf2f(h));
        }
        #pragma unroll
        for (int ct = 0; ct < 4; ++ct) {
            bf16x8 wf = *reinterpret_cast<const bf16x8*>(wp + (size_t)ct * 16 * 512 + kt);
            acc[ct] = __builtin_amdgcn_mfma_f32_16x16x32_bf16(ah, wf, acc[ct], 0, 0, 0);
            acc[ct] = __builtin_amdgcn_mfma_f32_16x16x32_bf16(al, wf, acc[ct], 0, 0, 0);
        }
    }

    // C-frag: col = lane&15, row = 4*(lane>>4)+reg  [guide m89]
    const int bb = r0 >> 12, n0 = r0 & 4095;
    if (colgrp < 2) {
        __hip_bfloat16* dst = (colgrp == 0) ? Qb : Kb;
        #pragma unroll
        for (int ct = 0; ct < 4; ++ct) {
            const float bias = bc[c0 + ct * 16 + lo];
            #pragma unroll
            for (int r = 0; r < 4; ++r) {
                short hv = f2bf(acc[ct][r] + bias);
                dst[(size_t)(r0 + 4 * g + r) * 64 + ct * 16 + lo] =
                    *reinterpret_cast<__hip_bfloat16*>(&hv);
            }
        }
    } else {
        #pragma unroll
        for (int ct = 0; ct < 4; ++ct) {
            const float bias = bc[128 + ct * 16 + lo];
            #pragma unroll
            for (int r = 0; r < 4; ++r)
                vt[w][(4 * g + r) * 64 + ct * 16 + lo] = f2bf(acc[ct][r] + bias);
        }
        asm volatile("s_waitcnt lgkmcnt(0)" ::: "memory");
        __builtin_amdgcn_sched_barrier(0);
        // lane = output channel a; gather its 16 n-values (2-way bank alias: free)
        unsigned u[8];
        #pragma unroll
        for (int n = 0; n < 8; ++n) {
            unsigned v0 = (unsigned short)vt[w][(2 * n) * 64 + lane];
            unsigned v1 = (unsigned short)vt[w][(2 * n + 1) * 64 + lane];
            u[n] = v0 | (v1 << 16);
        }
        uint4* dstv = reinterpret_cast<uint4*>(&Vt[((size_t)(bb * 64 + lane)) * 4096 + n0]);
        dstv[0] = uint4{u[0], u[1], u[2], u[3]};
        dstv[1] = uint4{u[4], u[5], u[6], u[7]};
    }
}

// ---------------------------------------------------------------------------
// Kernel 2: flash attention (no online max; scores bounded -> exp2 direct).
// WAVES waves/block, each wave 32 q-rows (2 q-tiles). K/V double-buffered in
// swizzled LDS shared by all waves. Swapped QK^T: cc = mfma(K,Q).
// Mapping is ks-FAST: ks = blockIdx % KS. With XCD = blockIdx % 8 and KS=8,
// each XCD touches exactly one K/V eighth (512 KB) -> L2-resident.
// One barrier per K-step (double-buffer makes the post-step barrier redundant).
// Pacc layout [ks][b*N+n][a]: float4 epilogue stores, streaming reduce.
// ---------------------------------------------------------------------------
template<int WAVES, int KS, bool DIRECT>
__global__ __launch_bounds__(WAVES * 64, 4) void attn(
    const __hip_bfloat16* __restrict__ Qb,
    const __hip_bfloat16* __restrict__ Kb,
    const __hip_bfloat16* __restrict__ Vt,
    float* __restrict__ Pacc, float* __restrict__ Lbuf, float* __restrict__ outD)
{
    constexpr int T    = WAVES * 64;
    constexpr int QPB  = WAVES * 32;
    constexpr int SBPB = Nn / QPB;
    constexpr int NC   = 512 / T;      // staging chunks per thread

    __shared__ __align__(16) short Klds[2][64 * 64];
    __shared__ __align__(16) short Vlds[2][64 * 64];
    __shared__ __align__(16) short Plds[WAVES][16 * 64];

    const int tid  = threadIdx.x;
    const int w    = tid >> 6, lane = tid & 63;
    const int lo   = lane & 15, g = lane >> 4;
    const int ks   = blockIdx.x % KS;          // ks-fast: XCD-pure K/V slices
    const int qsb  = blockIdx.x / KS;
    const int b    = qsb / SBPB;
    const int nqb  = (qsb % SBPB) * QPB;
    const int k0b  = ks * (Nn / KS);
    const int nsteps = (Nn / KS) / 64;

    bf16x8 qf[2][2];
    #pragma unroll
    for (int qt = 0; qt < 2; ++qt)
        #pragma unroll
        for (int dh = 0; dh < 2; ++dh)
            qf[qt][dh] = *reinterpret_cast<const bf16x8*>(
                &Qb[(size_t)(b * Nn + nqb + w * 32 + qt * 16 + lo) * 64 + dh * 32 + 8 * g]);

    f32x4 acc[2][4];
    #pragma unroll
    for (int q = 0; q < 2; ++q)
        #pragma unroll
        for (int a = 0; a < 4; ++a) acc[q][a] = f32x4{0.f, 0.f, 0.f, 0.f};
    float lsum[2] = {0.f, 0.f};

    uint4 kr[NC], vr[NC];
    auto stg_issue = [&](int s) {
        int k0 = k0b + s * 64;
        #pragma unroll
        for (int i = 0; i < NC; ++i) {
            int c = i * T + tid, key = c >> 3, sl = c & 7;
            kr[i] = *reinterpret_cast<const uint4*>(&Kb[(size_t)(b * Nn + k0 + key) * 64 + sl * 8]);
            vr[i] = *reinterpret_cast<const uint4*>(&Vt[(size_t)(b * 64 + key) * Nn + k0 + sl * 8]);
        }
    };
    auto stg_write = [&](int buf) {
        #pragma unroll
        for (int i = 0; i < NC; ++i) {
            int c = i * T + tid, key = c >> 3, ss = (c & 7) ^ (key & 7);
            *reinterpret_cast<uint4*>(&Klds[buf][key * 64 + ss * 8]) = kr[i];
            *reinterpret_cast<uint4*>(&Vlds[buf][key * 64 + ss * 8]) = vr[i];
        }
    };

    auto step = [&](int buf) {
        bf16x8 ka[4][2], va[4][2];
        #pragma unroll
        for (int t = 0; t < 4; ++t)
            #pragma unroll
            for (int dh = 0; dh < 2; ++dh) {
                int row = lo + 16 * t, ss = (g + 4 * dh) ^ (row & 7);
                ka[t][dh] = *reinterpret_cast<const bf16x8*>(&Klds[buf][row * 64 + ss * 8]);
            }
        #pragma unroll
        for (int at = 0; at < 4; ++at)
            #pragma unroll
            for (int c = 0; c < 2; ++c) {
                int row = at * 16 + lo, ss = (4 * c + g) ^ (row & 7);
                va[at][c] = *reinterpret_cast<const bf16x8*>(&Vlds[buf][row * 64 + ss * 8]);
            }
        char* pbase = reinterpret_cast<char*>(&Plds[w][0]) + lo * 128;
        #pragma unroll
        for (int qt = 0; qt < 2; ++qt) {
            f32x4 cc[4];
            #pragma unroll
            for (int t = 0; t < 4; ++t) {
                cc[t] = f32x4{0.f, 0.f, 0.f, 0.f};
                cc[t] = __builtin_amdgcn_mfma_f32_16x16x32_bf16(ka[t][0], qf[qt][0], cc[t], 0, 0, 0);
                cc[t] = __builtin_amdgcn_mfma_f32_16x16x32_bf16(ka[t][1], qf[qt][1], cc[t], 0, 0, 0);
            }
            #pragma unroll
            for (int t = 0; t < 4; ++t) {
                float p0 = exp2f(cc[t][0]), p1 = exp2f(cc[t][1]);
                float p2 = exp2f(cc[t][2]), p3 = exp2f(cc[t][3]);
                lsum[qt] += (p0 + p1) + (p2 + p3);
                uint2 pw = {pack2bf(p0, p1), pack2bf(p2, p3)};
                int byte = (32 * t + 8 * g) ^ ((lo & 7) << 4);
                *reinterpret_cast<uint2*>(pbase + byte) = pw;
            }
            asm volatile("s_waitcnt lgkmcnt(0)" ::: "memory");
            bf16x8 pb[2];
            #pragma unroll
            for (int c = 0; c < 2; ++c) {
                int byte = (64 * c + 16 * g) ^ ((lo & 7) << 4);
                pb[c] = *reinterpret_cast<const bf16x8*>(pbase + byte);
            }
            #pragma unroll
            for (int at = 0; at < 4; ++at) {
                acc[qt][at] = __builtin_amdgcn_mfma_f32_16x16x32_bf16(va[at][0], pb[0], acc[qt][at], 0, 0, 0);
                acc[qt][at] = __builtin_amdgcn_mfma_f32_16x16x32_bf16(va[at][1], pb[1], acc[qt][at], 0, 0, 0);
            }
        }
    };

    stg_issue(0);
    stg_write(0);
    __syncthreads();
    for (int s = 0; s < nsteps; ++s) {
        if (s + 1 < nsteps) stg_issue(s + 1);
        step(s & 1);
        if (s + 1 < nsteps) {
            // single barrier: write targets the buffer last read in step s-1,
            // already protected by the previous iteration's barrier.
            stg_write((s + 1) & 1);
            __syncthreads();
        }
    }

    #pragma unroll
    for (int qt = 0; qt < 2; ++qt) {
        float l = lsum[qt];
        l += __shfl_xor(l, 16);
        l += __shfl_xor(l, 32);
        const int n = nqb + w * 32 + qt * 16 + lo;
        const size_t ng = (size_t)b * Nn + n;
        if (!DIRECT) {
            if (g == 0) Lbuf[(size_t)ks * (Bn * Nn) + ng] = l;
            float* prow = Pacc + ((size_t)ks * (Bn * Nn) + ng) * 64;
            #pragma unroll
            for (int at = 0; at < 4; ++at)
                *reinterpret_cast<f32x4*>(prow + at * 16 + 4 * g) = acc[qt][at];
        } else {
            float inv = 1.0f / l;
            #pragma unroll
            for (int at = 0; at < 4; ++at) {
                f32x4 v = acc[qt][at] * inv;
                *reinterpret_cast<f32x4*>(&outD[ng * 64 + at * 16 + 4 * g]) = v;
            }
        }
    }
}

// ---------------------------------------------------------------------------
// Kernel 3: streaming combine of key-split partials (Pacc is [ks][n][a]).
// Fully coalesced float4 reads/writes, no LDS. 1024 blocks x 256 threads.
// ---------------------------------------------------------------------------
__global__ __launch_bounds__(256) void reduce_out(
    const float* __restrict__ Pacc, const float* __restrict__ Lbuf,
    float* __restrict__ out, int KS)
{
    const int idx = blockIdx.x * 256 + threadIdx.x;   // 262144 total
    const int ng  = idx >> 4;
    const int a4  = (idx & 15) * 4;
    f32x4 s = f32x4{0.f, 0.f, 0.f, 0.f};
    float l = 0.f;
    for (int k = 0; k < KS; ++k) {
        s += *reinterpret_cast<const f32x4*>(&Pacc[((size_t)k * (Bn * Nn) + ng) * 64 + a4]);
        l += Lbuf[(size_t)k * (Bn * Nn) + ng];
    }
    const float inv = 1.0f / l;
    *reinterpret_cast<f32x4*>(&out[(size_t)ng * 64 + a4]) = s * inv;
}

} // anonymous namespace

extern "C" void kernel_launch(void* const* d_in, const int* in_sizes, int n_in,
                              void* d_out, int out_size, void* d_ws, size_t ws_size,
                              hipStream_t stream) {
    const float* x  = (const float*)d_in[0];
    const float* Wq = (const float*)d_in[1];
    const float* bq = (const float*)d_in[2];
    const float* Wk = (const float*)d_in[3];
    const float* bk = (const float*)d_in[4];
    const float* Wv = (const float*)d_in[5];
    const float* bv = (const float*)d_in[6];
    float* out = (float*)d_out;

    char* ws = (char*)d_ws;
    const size_t mat_bytes = (size_t)Bn * Nn * An * sizeof(__hip_bfloat16);  // 2 MiB
    __hip_bfloat16* Qb = (__hip_bfloat16*)(ws);
    __hip_bfloat16* Kb = (__hip_bfloat16*)(ws + mat_bytes);
    __hip_bfloat16* Vt = (__hip_bfloat16*)(ws + 2 * mat_bytes);
    float* Pacc = (float*)(ws + 3 * mat_bytes);
    const size_t pacc_bytes = (size_t)Bn * Nn * An * sizeof(float);          // 4 MiB per split
    const size_t lbuf_per   = (size_t)Bn * Nn * sizeof(float);               // 64 KiB per split

    // weight-pack scratch in d_out (consumed by qkv_mm, later overwritten)
    short* Wt = (short*)d_out;
    float* bc = (float*)((char*)d_out + 192 * 512 * 2);

    wpack<<<dim3(48), dim3(256), 0, stream>>>(Wq, bq, Wk, bk, Wv, bv, Wt, bc);
    qkv_mm<<<dim3(768), dim3(256), 0, stream>>>(x, Wt, bc, Qb, Kb, Vt);

    const size_t base = 3 * mat_bytes;
    const int rgrid = (Bn * Nn * An) / (4 * 256);   // 1024
    if (ws_size >= base + 8 * (pacc_bytes + lbuf_per)) {
        float* Lbuf = (float*)(ws + base + 8 * pacc_bytes);
        attn<8, 8, false><<<dim3((Bn * Nn / 256) * 8), dim3(512), 0, stream>>>(Qb, Kb, Vt, Pacc, Lbuf, out);
        reduce_out<<<dim3(rgrid), dim3(256), 0, stream>>>(Pacc, Lbuf, out, 8);
    } else if (ws_size >= base + 4 * (pacc_bytes + lbuf_per)) {
        float* Lbuf = (float*)(ws + base + 4 * pacc_bytes);
        attn<8, 4, false><<<dim3((Bn * Nn / 256) * 4), dim3(512), 0, stream>>>(Qb, Kb, Vt, Pacc, Lbuf, out);
        reduce_out<<<dim3(rgrid), dim3(256), 0, stream>>>(Pacc, Lbuf, out, 4);
    } else {
        attn<4, 1, true><<<dim3(Bn * Nn / 128), dim3(256), 0, stream>>>(Qb, Kb, Vt, nullptr, nullptr, out);
    }
}